// Round 25
// baseline (203.615 us; speedup 1.0000x reference)
//
#include <hip/hip_runtime.h>
#include <hip/hip_bf16.h>
#include <math.h>

#define B_ 4
#define S_ 4096
#define D_ 768
#define U_ 64
#define TK 32
#define NT (S_ / TK)
#define XT_TILE (TK * D_)
#define QK_TILE 2048
#define PSTR 776

typedef __attribute__((ext_vector_type(8))) short short8;
typedef __attribute__((ext_vector_type(16))) float f32x16;
typedef __attribute__((ext_vector_type(2))) unsigned int uint2v;

__device__ __forceinline__ unsigned short f2bf(float f) {
    unsigned int x = __float_as_uint(f);
    unsigned int r = (x + 0x7fffu + ((x >> 16) & 1u)) >> 16;
    return (unsigned short)r;
}

// ---- kernel Z: zero the output ----
__global__ __launch_bounds__(256) void zero_k(float4* __restrict__ out, int n4) {
    int i = blockIdx.x * 256 + threadIdx.x;
    const int stride = gridDim.x * 256;
    const float4 z = make_float4(0.f, 0.f, 0.f, 0.f);
    for (; i < n4; i += stride) out[i] = z;
}

// ---- kernel S: per-batch mask scan -> invK, NV ----
__global__ __launch_bounds__(256) void scan_k(const unsigned char* __restrict__ mraw,
                                              int* __restrict__ invK,
                                              int* __restrict__ nvbuf) {
    __shared__ int wsum[4];
    const int tid = threadIdx.x;
    const int b = blockIdx.x;
    int base = tid * 4;
    int bad = (mraw[base + 1] | mraw[base + 2] | mraw[base + 3]) != 0;
    int isbyte = __syncthreads_or(bad);
    int v[16]; int cnt = 0;
    const int s0 = tid * 16;
    #pragma unroll
    for (int e = 0; e < 16; ++e) {
        const int s = s0 + e;
        const int m = isbyte ? (int)mraw[b * S_ + s] : ((const int*)mraw)[b * S_ + s];
        v[e] = (m != 0); cnt += v[e];
    }
    int inc = cnt;
    #pragma unroll
    for (int off = 1; off < 64; off <<= 1) {
        const int y = __shfl_up(inc, off);
        if ((tid & 63) >= off) inc += y;
    }
    if ((tid & 63) == 63) wsum[tid >> 6] = inc;
    __syncthreads();
    int wbase = 0;
    #pragma unroll
    for (int ww = 0; ww < 4; ++ww) if (ww < (tid >> 6)) wbase += wsum[ww];
    int pos = wbase + inc - cnt;
    #pragma unroll
    for (int e = 0; e < 16; ++e)
        if (v[e]) { invK[b * S_ + pos] = s0 + e; ++pos; }
    if (tid == 255) nvbuf[b] = wbase + inc;
}

// ---- kernel W: Wq/Wk -> 32x32x16 B-fragments ----
__global__ __launch_bounds__(256) void wfrag_k(const float* __restrict__ Wq,
                                               const float* __restrict__ Wk,
                                               unsigned short* __restrict__ wfg) {
    const int gid = blockIdx.x * 256 + threadIdx.x;
    const int fg = gid >> 6;
    const int l = gid & 63;
    const int m2 = fg / 96;
    const int rem = fg % 96;
    const int ut = rem / 48;
    const int kk = rem % 48;
    const float* __restrict__ W = m2 ? Wk : Wq;
    short8 v;
    #pragma unroll
    for (int e = 0; e < 8; ++e)
        v[e] = (short)f2bf(W[(kk * 16 + (l >> 5) * 8 + e) * U_ + ut * 32 + (l & 31)]);
    *(short8*)&wfg[(size_t)fg * 512 + l * 8] = v;
}

// ---- kernel P: compacted prep (unchanged) ----
__global__ __launch_bounds__(256) void prep_k(const float* __restrict__ x,
                                              const int* __restrict__ invK,
                                              const int* __restrict__ nvbuf,
                                              const unsigned short* __restrict__ wfg,
                                              unsigned short* __restrict__ qg,
                                              unsigned short* __restrict__ kg,
                                              unsigned short* __restrict__ xTg) {
    const int blk = blockIdx.x;
    const int b = blk >> 7;
    const int ct = blk & 127;
    const int NV = nvbuf[b];
    if (ct * 32 >= NV) return;
    __shared__ unsigned short xs[32][PSTR];
    const int tid = threadIdx.x;
    {
        const int row = tid >> 3;
        const int c8 = tid & 7;
        const int cpos = min(ct * 32 + row, NV - 1);
        const int srow = invK[b * S_ + cpos];
        const float* xsrc = x + ((size_t)(b * S_ + srow)) * D_;
        #pragma unroll
        for (int it = 0; it < 24; ++it) {
            const int col = (c8 + it * 8) * 4;
            const float4 vv = *(const float4*)&xsrc[col];
            const unsigned int lo = __builtin_amdgcn_perm(
                __float_as_uint(vv.y) + 0x8000u, __float_as_uint(vv.x) + 0x8000u, 0x07060302u);
            const unsigned int hiw = __builtin_amdgcn_perm(
                __float_as_uint(vv.w) + 0x8000u, __float_as_uint(vv.z) + 0x8000u, 0x07060302u);
            *(uint2*)&xs[row][col] = make_uint2(lo, hiw);
        }
    }
    __syncthreads();
    {
        unsigned short* dst = xTg + (size_t)(b * NT + ct) * XT_TILE;
        #pragma unroll
        for (int it = 0; it < 12; ++it) {
            const int idx = it * 256 + tid;
            const int col = idx & 31;
            const int kh  = (idx >> 5) & 1;
            const int db  = (idx >> 6) % 24;
            const int kw  = idx / 1536;
            const int d   = db * 32 + col;
            const int sr  = kw * 16 + kh * 8;
            short8 v;
            #pragma unroll
            for (int e = 0; e < 8; ++e) v[e] = (short)xs[sr + e][d];
            *(short8*)&dst[idx * 8] = v;
        }
    }
    {
        const int w = tid >> 6;
        const int l = tid & 63;
        const unsigned short* wfb = wfg + (size_t)w * 48 * 512;
        f32x16 acc0 = {0.f}, acc1 = {0.f};
        #pragma unroll 4
        for (int kk = 0; kk < 48; kk += 2) {
            const short8 a0 = *(const short8*)&xs[l & 31][kk * 16 + (l >> 5) * 8];
            const short8 b0 = *(const short8*)&wfb[kk * 512 + l * 8];
            acc0 = __builtin_amdgcn_mfma_f32_32x32x16_bf16(a0, b0, acc0, 0, 0, 0);
            const short8 a1 = *(const short8*)&xs[l & 31][(kk + 1) * 16 + (l >> 5) * 8];
            const short8 b1 = *(const short8*)&wfb[(kk + 1) * 512 + l * 8];
            acc1 = __builtin_amdgcn_mfma_f32_32x32x16_bf16(a1, b1, acc1, 0, 0, 0);
        }
        const int ut = w & 1;
        unsigned short* dstqk = ((w >> 1) ? kg : qg) + (size_t)(b * NT + ct) * QK_TILE;
        const int mfrag = ut * 2 + ((l >> 4) & 1);
        const int b3 = (l >> 3) & 1;
        const int e  = l & 7;
        #pragma unroll
        for (int r = 0; r < 16; ++r) {
            const int row = (r & 3) + 8 * (r >> 2) + 4 * (l >> 5);
            dstqk[(mfrag * 64 + row + 32 * b3) * 8 + e] = f2bf(acc0[r] + acc1[r]);
        }
    }
}

// ---- kernel A: compacted flash, no-bias fast path + peeled partial tile.
//      1024 blocks x 256 thr; 4 waves = ks x dg(96 cols, acc[3]); 4 waves/SIMD target. ----
__global__ __launch_bounds__(256, 4) void attn_k(const unsigned short* __restrict__ xTg,
                                                 const unsigned short* __restrict__ qg,
                                                 const unsigned short* __restrict__ kg,
                                                 const int* __restrict__ invK,
                                                 const int* __restrict__ nvbuf,
                                                 float* __restrict__ out) {
    __shared__ float sc_l[32];
    __shared__ float lsum[32];
    __shared__ int   is_l[32];
    __shared__ __align__(16) float am_l[2][64][20];

    const int tid = threadIdx.x;
    const int w = tid >> 6;
    const int l = tid & 63;
    const int hi = l >> 5;
    const int q5 = l & 31;
    const int ks = w >> 1;
    const int dg = w & 1;
    const int raw = blockIdx.x;
    const int bh = raw & 7;
    const int b = bh >> 1;
    const int par = bh & 1;
    const int idx = raw >> 3;
    const int dq = idx & 3;
    const int qt0 = ((idx >> 2) << 1) + par;
    const int db0 = dq * 6 + dg * 3;
    const int NV = nvbuf[b];
    const int ntc = (NV + 31) >> 5;
    const int htc = ntc >> 1;
    const int nfull_t = NV >> 5;                    // total fully-valid tiles

    const unsigned short* xT_b = xTg + (size_t)b * NT * XT_TILE;
    const unsigned short* kg_b = kg + (size_t)(b * NT) * QK_TILE;
    const float SCL2 = 0.125f * 1.4426950408889634f;

    const int nfull = ks ? (nfull_t - htc) : htc;   // full tiles in my range
    const int tb = ks ? htc : 0;

    for (int qt = qt0; qt < NT; qt += 64) {
        if (qt * 32 >= NV) continue;
        const int q0 = qt * 32;

        short8 qf[4];
        {
            const unsigned short* qp = qg + (size_t)(b * NT + qt) * QK_TILE;
            #pragma unroll
            for (int m = 0; m < 4; ++m) qf[m] = *(const short8*)(qp + (m * 64 + l) * 8);
        }
        f32x16 acc[3];
        {
            f32x16 z = {0.f};
            #pragma unroll
            for (int j = 0; j < 3; ++j) acc[j] = z;
        }
        float l_run = 0.f;

        short8 kfA[4], kfB[4];
        {
            const unsigned short* kp = kg_b + (size_t)tb * QK_TILE;
            #pragma unroll
            for (int m = 0; m < 4; ++m) kfA[m] = *(const short8*)(kp + (m * 64 + l) * 8);
        }

        // shared tail of every step: softmax (from c), pack, PV
        auto finish = [&](const f32x16& c, const short8 (&xv)[6], int kv) {
            float ps = 0.f;
            unsigned int W[8];
            #pragma unroll
            for (int j = 0; j < 8; ++j) {
                const int r0 = 2 * j, r1 = 2 * j + 1;
                float pa = exp2f(c[r0] * SCL2);
                float pb = exp2f(c[r1] * SCL2);
                if (kv < 32) {   // partial tile: zero invalid keys (wave-uniform branch)
                    const int k0 = (r0 & 3) + 8 * (r0 >> 2) + 4 * hi;
                    const int k1 = (r1 & 3) + 8 * (r1 >> 2) + 4 * hi;
                    pa = (k0 < kv) ? pa : 0.f;
                    pb = (k1 < kv) ? pb : 0.f;
                }
                ps += pa + pb;
                W[j] = __builtin_amdgcn_perm(__float_as_uint(pb), __float_as_uint(pa),
                                             0x07060302u);
            }
            ps += __shfl_xor(ps, 32);
            l_run += ps;
            const uint2v s02 = __builtin_amdgcn_permlane32_swap(W[0], W[2], false, false);
            const uint2v s13 = __builtin_amdgcn_permlane32_swap(W[1], W[3], false, false);
            const uint2v s46 = __builtin_amdgcn_permlane32_swap(W[4], W[6], false, false);
            const uint2v s57 = __builtin_amdgcn_permlane32_swap(W[5], W[7], false, false);
            union U4 { unsigned int u[4]; short8 v; };
            U4 a0, a1;
            a0.u[0] = s02.x; a0.u[1] = s13.x; a0.u[2] = s02.y; a0.u[3] = s13.y;
            a1.u[0] = s46.x; a1.u[1] = s57.x; a1.u[2] = s46.y; a1.u[3] = s57.y;
            #pragma unroll
            for (int j = 0; j < 3; ++j) {
                acc[j] = __builtin_amdgcn_mfma_f32_32x32x16_bf16(a0.v, xv[j], acc[j], 0, 0, 0);
                acc[j] = __builtin_amdgcn_mfma_f32_32x32x16_bf16(a1.v, xv[3 + j], acc[j], 0, 0, 0);
            }
        };

        auto step = [&](int tt, int tn, short8 (&kcur)[4], short8 (&knxt)[4]) {
            const unsigned short* xt = xT_b + (size_t)tt * XT_TILE;
            short8 xv[6];
            #pragma unroll
            for (int kw = 0; kw < 2; ++kw)
                #pragma unroll
                for (int j = 0; j < 3; ++j)
                    xv[kw * 3 + j] = *(const short8*)(xt + ((kw * 24 + db0 + j) * 64 + l) * 8);
            const unsigned short* kp = kg_b + (size_t)tn * QK_TILE;
            #pragma unroll
            for (int m = 0; m < 4; ++m) knxt[m] = *(const short8*)(kp + (m * 64 + l) * 8);
            f32x16 c = {0.f};
            #pragma unroll
            for (int m = 0; m < 4; ++m)
                c = __builtin_amdgcn_mfma_f32_32x32x16_bf16(kcur[m], qf[m], c, 0, 0, 0);
            finish(c, xv, 32);
        };

        int it = 0;
        for (; it + 1 < nfull; it += 2) {
            step(tb + it, tb + it + 1, kfA, kfB);
            step(tb + it + 1, (it + 2 < nfull) ? tb + it + 2 : tb, kfB, kfA);
        }
        if (it < nfull) step(tb + it, tb, kfA, kfB);

        // peeled partial tile (ks=1 only; loads its own k, zero-masks by key index)
        if (ks && (NV & 31)) {
            const int tt = ntc - 1;
            short8 kp4[4];
            const unsigned short* kp = kg_b + (size_t)tt * QK_TILE;
            #pragma unroll
            for (int m = 0; m < 4; ++m) kp4[m] = *(const short8*)(kp + (m * 64 + l) * 8);
            const unsigned short* xt = xT_b + (size_t)tt * XT_TILE;
            short8 xv[6];
            #pragma unroll
            for (int kw = 0; kw < 2; ++kw)
                #pragma unroll
                for (int j = 0; j < 3; ++j)
                    xv[kw * 3 + j] = *(const short8*)(xt + ((kw * 24 + db0 + j) * 64 + l) * 8);
            f32x16 c = {0.f};
            #pragma unroll
            for (int m = 0; m < 4; ++m)
                c = __builtin_amdgcn_mfma_f32_32x32x16_bf16(kp4[m], qf[m], c, 0, 0, 0);
            finish(c, xv, NV & 31);
        }

        // ---------- sum-merge epilogue ----------
        if (w == 2 && !hi) lsum[q5] = l_run;
        if (w == 0 && !hi) is_l[q5] = (q0 + q5 < NV) ? invK[b * S_ + q0 + q5] : -1;
        __syncthreads();
        if (w == 0 && !hi) {
            const float lt = l_run + lsum[q5];
            sc_l[q5] = (lt > 0.f) ? (1.f / lt) : 0.f;
        }
        __syncthreads();
        #pragma unroll
        for (int j = 0; j < 3; ++j) {
            if (ks) {
                #pragma unroll
                for (int g = 0; g < 4; ++g)
                    *(float4*)&am_l[dg][l][g * 4] =
                        make_float4(acc[j][g * 4 + 0], acc[j][g * 4 + 1],
                                    acc[j][g * 4 + 2], acc[j][g * 4 + 3]);
            }
            __syncthreads();
            if (!ks) {
                float4 iv[4];
                #pragma unroll
                for (int g = 0; g < 4; ++g) iv[g] = *(const float4*)&sc_l[g * 8 + hi * 4];
                const int dcol = (db0 + j) * 32 + q5;
                #pragma unroll
                for (int g = 0; g < 4; ++g) {
                    const float4 ab = *(const float4*)&am_l[dg][l][g * 4];
                    #pragma unroll
                    for (int e = 0; e < 4; ++e) {
                        const int r = g * 4 + e;
                        const int qr = (r & 3) + 8 * (r >> 2) + 4 * hi;
                        const int srow = is_l[qr];
                        if (srow >= 0)
                            out[(size_t)(b * S_ + srow) * D_ + dcol] =
                                (acc[j][r] + ((const float*)&ab)[e]) *
                                ((const float*)&iv[g])[e];
                    }
                }
            }
            __syncthreads();
        }
    }
}

extern "C" void kernel_launch(void* const* d_in, const int* in_sizes, int n_in,
                              void* d_out, int out_size, void* d_ws, size_t ws_size,
                              hipStream_t stream) {
    const float*         x    = (const float*)d_in[0];
    const unsigned char* mraw = (const unsigned char*)d_in[1];
    const float*         Wq   = (const float*)d_in[2];
    const float*         Wk   = (const float*)d_in[3];
    float*               outp = (float*)d_out;

    int* invK = (int*)d_ws;
    int* nvbuf = invK + (size_t)B_ * S_;
    unsigned short* qg  = (unsigned short*)(nvbuf + 16);
    unsigned short* kg  = qg + (size_t)B_ * S_ * U_;
    unsigned short* xTg = kg + (size_t)B_ * S_ * U_;
    unsigned short* wfg = xTg + (size_t)B_ * S_ * D_;

    zero_k<<<2048, 256, 0, stream>>>((float4*)outp, B_ * S_ * D_ / 4);
    scan_k<<<B_, 256, 0, stream>>>(mraw, invK, nvbuf);
    wfrag_k<<<48, 256, 0, stream>>>(Wq, Wk, wfg);
    prep_k<<<B_ * NT, 256, 0, stream>>>(x, invK, nvbuf, wfg, qg, kg, xTg);
    attn_k<<<1024, 256, 0, stream>>>(xTg, qg, kg, invK, nvbuf, outp);
}

// Round 26
// 126.844 us; speedup vs baseline: 1.6052x; 1.6052x over previous
//
#include <hip/hip_runtime.h>
#include <hip/hip_bf16.h>
#include <math.h>

#define B_ 4
#define S_ 4096
#define D_ 768
#define U_ 64
#define TK 32
#define NT (S_ / TK)
#define XT_TILE (TK * D_)
#define QK_TILE 2048
#define PSTR 776

typedef __attribute__((ext_vector_type(8))) short short8;
typedef __attribute__((ext_vector_type(16))) float f32x16;
typedef __attribute__((ext_vector_type(2))) unsigned int uint2v;

__device__ __forceinline__ unsigned short f2bf(float f) {
    unsigned int x = __float_as_uint(f);
    unsigned int r = (x + 0x7fffu + ((x >> 16) & 1u)) >> 16;
    return (unsigned short)r;
}

// ---- kernel Z: zero the output ----
__global__ __launch_bounds__(256) void zero_k(float4* __restrict__ out, int n4) {
    int i = blockIdx.x * 256 + threadIdx.x;
    const int stride = gridDim.x * 256;
    const float4 z = make_float4(0.f, 0.f, 0.f, 0.f);
    for (; i < n4; i += stride) out[i] = z;
}

// ---- kernel S: per-batch mask scan -> invK, NV ----
__global__ __launch_bounds__(256) void scan_k(const unsigned char* __restrict__ mraw,
                                              int* __restrict__ invK,
                                              int* __restrict__ nvbuf) {
    __shared__ int wsum[4];
    const int tid = threadIdx.x;
    const int b = blockIdx.x;
    int base = tid * 4;
    int bad = (mraw[base + 1] | mraw[base + 2] | mraw[base + 3]) != 0;
    int isbyte = __syncthreads_or(bad);
    int v[16]; int cnt = 0;
    const int s0 = tid * 16;
    #pragma unroll
    for (int e = 0; e < 16; ++e) {
        const int s = s0 + e;
        const int m = isbyte ? (int)mraw[b * S_ + s] : ((const int*)mraw)[b * S_ + s];
        v[e] = (m != 0); cnt += v[e];
    }
    int inc = cnt;
    #pragma unroll
    for (int off = 1; off < 64; off <<= 1) {
        const int y = __shfl_up(inc, off);
        if ((tid & 63) >= off) inc += y;
    }
    if ((tid & 63) == 63) wsum[tid >> 6] = inc;
    __syncthreads();
    int wbase = 0;
    #pragma unroll
    for (int ww = 0; ww < 4; ++ww) if (ww < (tid >> 6)) wbase += wsum[ww];
    int pos = wbase + inc - cnt;
    #pragma unroll
    for (int e = 0; e < 16; ++e)
        if (v[e]) { invK[b * S_ + pos] = s0 + e; ++pos; }
    if (tid == 255) nvbuf[b] = wbase + inc;
}

// ---- kernel W: Wq/Wk -> 32x32x16 B-fragments ----
__global__ __launch_bounds__(256) void wfrag_k(const float* __restrict__ Wq,
                                               const float* __restrict__ Wk,
                                               unsigned short* __restrict__ wfg) {
    const int gid = blockIdx.x * 256 + threadIdx.x;
    const int fg = gid >> 6;
    const int l = gid & 63;
    const int m2 = fg / 96;
    const int rem = fg % 96;
    const int ut = rem / 48;
    const int kk = rem % 48;
    const float* __restrict__ W = m2 ? Wk : Wq;
    short8 v;
    #pragma unroll
    for (int e = 0; e < 8; ++e)
        v[e] = (short)f2bf(W[(kk * 16 + (l >> 5) * 8 + e) * U_ + ut * 32 + (l & 31)]);
    *(short8*)&wfg[(size_t)fg * 512 + l * 8] = v;
}

// ---- kernel P: compacted prep (unchanged) ----
__global__ __launch_bounds__(256) void prep_k(const float* __restrict__ x,
                                              const int* __restrict__ invK,
                                              const int* __restrict__ nvbuf,
                                              const unsigned short* __restrict__ wfg,
                                              unsigned short* __restrict__ qg,
                                              unsigned short* __restrict__ kg,
                                              unsigned short* __restrict__ xTg) {
    const int blk = blockIdx.x;
    const int b = blk >> 7;
    const int ct = blk & 127;
    const int NV = nvbuf[b];
    if (ct * 32 >= NV) return;
    __shared__ unsigned short xs[32][PSTR];
    const int tid = threadIdx.x;
    {
        const int row = tid >> 3;
        const int c8 = tid & 7;
        const int cpos = min(ct * 32 + row, NV - 1);
        const int srow = invK[b * S_ + cpos];
        const float* xsrc = x + ((size_t)(b * S_ + srow)) * D_;
        #pragma unroll
        for (int it = 0; it < 24; ++it) {
            const int col = (c8 + it * 8) * 4;
            const float4 vv = *(const float4*)&xsrc[col];
            const unsigned int lo = __builtin_amdgcn_perm(
                __float_as_uint(vv.y) + 0x8000u, __float_as_uint(vv.x) + 0x8000u, 0x07060302u);
            const unsigned int hiw = __builtin_amdgcn_perm(
                __float_as_uint(vv.w) + 0x8000u, __float_as_uint(vv.z) + 0x8000u, 0x07060302u);
            *(uint2*)&xs[row][col] = make_uint2(lo, hiw);
        }
    }
    __syncthreads();
    {
        unsigned short* dst = xTg + (size_t)(b * NT + ct) * XT_TILE;
        #pragma unroll
        for (int it = 0; it < 12; ++it) {
            const int idx = it * 256 + tid;
            const int col = idx & 31;
            const int kh  = (idx >> 5) & 1;
            const int db  = (idx >> 6) % 24;
            const int kw  = idx / 1536;
            const int d   = db * 32 + col;
            const int sr  = kw * 16 + kh * 8;
            short8 v;
            #pragma unroll
            for (int e = 0; e < 8; ++e) v[e] = (short)xs[sr + e][d];
            *(short8*)&dst[idx * 8] = v;
        }
    }
    {
        const int w = tid >> 6;
        const int l = tid & 63;
        const unsigned short* wfb = wfg + (size_t)w * 48 * 512;
        f32x16 acc0 = {0.f}, acc1 = {0.f};
        #pragma unroll 4
        for (int kk = 0; kk < 48; kk += 2) {
            const short8 a0 = *(const short8*)&xs[l & 31][kk * 16 + (l >> 5) * 8];
            const short8 b0 = *(const short8*)&wfb[kk * 512 + l * 8];
            acc0 = __builtin_amdgcn_mfma_f32_32x32x16_bf16(a0, b0, acc0, 0, 0, 0);
            const short8 a1 = *(const short8*)&xs[l & 31][(kk + 1) * 16 + (l >> 5) * 8];
            const short8 b1 = *(const short8*)&wfb[(kk + 1) * 512 + l * 8];
            acc1 = __builtin_amdgcn_mfma_f32_32x32x16_bf16(a1, b1, acc1, 0, 0, 0);
        }
        const int ut = w & 1;
        unsigned short* dstqk = ((w >> 1) ? kg : qg) + (size_t)(b * NT + ct) * QK_TILE;
        const int mfrag = ut * 2 + ((l >> 4) & 1);
        const int b3 = (l >> 3) & 1;
        const int e  = l & 7;
        #pragma unroll
        for (int r = 0; r < 16; ++r) {
            const int row = (r & 3) + 8 * (r >> 2) + 4 * (l >> 5);
            dstqk[(mfrag * 64 + row + 32 * b3) * 8 + e] = f2bf(acc0[r] + acc1[r]);
        }
    }
}

// ---- kernel A: compacted flash, no-bias fast path + peeled partial tile.
//      1024 blocks x 256 thr; 4 waves = ks x dg(96 cols, acc[3]); 3 waves/SIMD (proven). ----
__global__ __launch_bounds__(256, 3) void attn_k(const unsigned short* __restrict__ xTg,
                                                 const unsigned short* __restrict__ qg,
                                                 const unsigned short* __restrict__ kg,
                                                 const int* __restrict__ invK,
                                                 const int* __restrict__ nvbuf,
                                                 float* __restrict__ out) {
    __shared__ float sc_l[32];
    __shared__ float lsum[32];
    __shared__ int   is_l[32];
    __shared__ __align__(16) float am_l[2][64][20];

    const int tid = threadIdx.x;
    const int w = tid >> 6;
    const int l = tid & 63;
    const int hi = l >> 5;
    const int q5 = l & 31;
    const int ks = w >> 1;
    const int dg = w & 1;
    const int raw = blockIdx.x;
    const int bh = raw & 7;
    const int b = bh >> 1;
    const int par = bh & 1;
    const int idx = raw >> 3;
    const int dq = idx & 3;
    const int qt0 = ((idx >> 2) << 1) + par;
    const int db0 = dq * 6 + dg * 3;
    const int NV = nvbuf[b];
    const int ntc = (NV + 31) >> 5;
    const int htc = ntc >> 1;
    const int nfull_t = NV >> 5;

    const unsigned short* xT_b = xTg + (size_t)b * NT * XT_TILE;
    const unsigned short* kg_b = kg + (size_t)(b * NT) * QK_TILE;
    const float SCL2 = 0.125f * 1.4426950408889634f;

    const int nfull = ks ? (nfull_t - htc) : htc;
    const int tb = ks ? htc : 0;

    for (int qt = qt0; qt < NT; qt += 64) {
        if (qt * 32 >= NV) continue;
        const int q0 = qt * 32;

        short8 qf[4];
        {
            const unsigned short* qp = qg + (size_t)(b * NT + qt) * QK_TILE;
            #pragma unroll
            for (int m = 0; m < 4; ++m) qf[m] = *(const short8*)(qp + (m * 64 + l) * 8);
        }
        f32x16 acc[3];
        {
            f32x16 z = {0.f};
            #pragma unroll
            for (int j = 0; j < 3; ++j) acc[j] = z;
        }
        float l_run = 0.f;

        short8 kfA[4], kfB[4];
        {
            const unsigned short* kp = kg_b + (size_t)tb * QK_TILE;
            #pragma unroll
            for (int m = 0; m < 4; ++m) kfA[m] = *(const short8*)(kp + (m * 64 + l) * 8);
        }

        auto finish = [&](const f32x16& c, const short8 (&xv)[6], int kv) {
            float ps = 0.f;
            unsigned int W[8];
            #pragma unroll
            for (int j = 0; j < 8; ++j) {
                const int r0 = 2 * j, r1 = 2 * j + 1;
                float pa = exp2f(c[r0] * SCL2);
                float pb = exp2f(c[r1] * SCL2);
                if (kv < 32) {
                    const int k0 = (r0 & 3) + 8 * (r0 >> 2) + 4 * hi;
                    const int k1 = (r1 & 3) + 8 * (r1 >> 2) + 4 * hi;
                    pa = (k0 < kv) ? pa : 0.f;
                    pb = (k1 < kv) ? pb : 0.f;
                }
                ps += pa + pb;
                W[j] = __builtin_amdgcn_perm(__float_as_uint(pb), __float_as_uint(pa),
                                             0x07060302u);
            }
            ps += __shfl_xor(ps, 32);
            l_run += ps;
            const uint2v s02 = __builtin_amdgcn_permlane32_swap(W[0], W[2], false, false);
            const uint2v s13 = __builtin_amdgcn_permlane32_swap(W[1], W[3], false, false);
            const uint2v s46 = __builtin_amdgcn_permlane32_swap(W[4], W[6], false, false);
            const uint2v s57 = __builtin_amdgcn_permlane32_swap(W[5], W[7], false, false);
            union U4 { unsigned int u[4]; short8 v; };
            U4 a0, a1;
            a0.u[0] = s02.x; a0.u[1] = s13.x; a0.u[2] = s02.y; a0.u[3] = s13.y;
            a1.u[0] = s46.x; a1.u[1] = s57.x; a1.u[2] = s46.y; a1.u[3] = s57.y;
            #pragma unroll
            for (int j = 0; j < 3; ++j) {
                acc[j] = __builtin_amdgcn_mfma_f32_32x32x16_bf16(a0.v, xv[j], acc[j], 0, 0, 0);
                acc[j] = __builtin_amdgcn_mfma_f32_32x32x16_bf16(a1.v, xv[3 + j], acc[j], 0, 0, 0);
            }
        };

        auto step = [&](int tt, int tn, short8 (&kcur)[4], short8 (&knxt)[4]) {
            const unsigned short* xt = xT_b + (size_t)tt * XT_TILE;
            short8 xv[6];
            #pragma unroll
            for (int kw = 0; kw < 2; ++kw)
                #pragma unroll
                for (int j = 0; j < 3; ++j)
                    xv[kw * 3 + j] = *(const short8*)(xt + ((kw * 24 + db0 + j) * 64 + l) * 8);
            const unsigned short* kp = kg_b + (size_t)tn * QK_TILE;
            #pragma unroll
            for (int m = 0; m < 4; ++m) knxt[m] = *(const short8*)(kp + (m * 64 + l) * 8);
            f32x16 c = {0.f};
            #pragma unroll
            for (int m = 0; m < 4; ++m)
                c = __builtin_amdgcn_mfma_f32_32x32x16_bf16(kcur[m], qf[m], c, 0, 0, 0);
            finish(c, xv, 32);
        };

        int it = 0;
        for (; it + 1 < nfull; it += 2) {
            step(tb + it, tb + it + 1, kfA, kfB);
            step(tb + it + 1, (it + 2 < nfull) ? tb + it + 2 : tb, kfB, kfA);
        }
        if (it < nfull) step(tb + it, tb, kfA, kfB);

        if (ks && (NV & 31)) {
            const int tt = ntc - 1;
            short8 kp4[4];
            const unsigned short* kp = kg_b + (size_t)tt * QK_TILE;
            #pragma unroll
            for (int m = 0; m < 4; ++m) kp4[m] = *(const short8*)(kp + (m * 64 + l) * 8);
            const unsigned short* xt = xT_b + (size_t)tt * XT_TILE;
            short8 xv[6];
            #pragma unroll
            for (int kw = 0; kw < 2; ++kw)
                #pragma unroll
                for (int j = 0; j < 3; ++j)
                    xv[kw * 3 + j] = *(const short8*)(xt + ((kw * 24 + db0 + j) * 64 + l) * 8);
            f32x16 c = {0.f};
            #pragma unroll
            for (int m = 0; m < 4; ++m)
                c = __builtin_amdgcn_mfma_f32_32x32x16_bf16(kp4[m], qf[m], c, 0, 0, 0);
            finish(c, xv, NV & 31);
        }

        // ---------- sum-merge epilogue ----------
        if (w == 2 && !hi) lsum[q5] = l_run;
        if (w == 0 && !hi) is_l[q5] = (q0 + q5 < NV) ? invK[b * S_ + q0 + q5] : -1;
        __syncthreads();
        if (w == 0 && !hi) {
            const float lt = l_run + lsum[q5];
            sc_l[q5] = (lt > 0.f) ? (1.f / lt) : 0.f;
        }
        __syncthreads();
        #pragma unroll
        for (int j = 0; j < 3; ++j) {
            if (ks) {
                #pragma unroll
                for (int g = 0; g < 4; ++g)
                    *(float4*)&am_l[dg][l][g * 4] =
                        make_float4(acc[j][g * 4 + 0], acc[j][g * 4 + 1],
                                    acc[j][g * 4 + 2], acc[j][g * 4 + 3]);
            }
            __syncthreads();
            if (!ks) {
                float4 iv[4];
                #pragma unroll
                for (int g = 0; g < 4; ++g) iv[g] = *(const float4*)&sc_l[g * 8 + hi * 4];
                const int dcol = (db0 + j) * 32 + q5;
                #pragma unroll
                for (int g = 0; g < 4; ++g) {
                    const float4 ab = *(const float4*)&am_l[dg][l][g * 4];
                    #pragma unroll
                    for (int e = 0; e < 4; ++e) {
                        const int r = g * 4 + e;
                        const int qr = (r & 3) + 8 * (r >> 2) + 4 * hi;
                        const int srow = is_l[qr];
                        if (srow >= 0)
                            out[(size_t)(b * S_ + srow) * D_ + dcol] =
                                (acc[j][r] + ((const float*)&ab)[e]) *
                                ((const float*)&iv[g])[e];
                    }
                }
            }
            __syncthreads();
        }
    }
}

extern "C" void kernel_launch(void* const* d_in, const int* in_sizes, int n_in,
                              void* d_out, int out_size, void* d_ws, size_t ws_size,
                              hipStream_t stream) {
    const float*         x    = (const float*)d_in[0];
    const unsigned char* mraw = (const unsigned char*)d_in[1];
    const float*         Wq   = (const float*)d_in[2];
    const float*         Wk   = (const float*)d_in[3];
    float*               outp = (float*)d_out;

    int* invK = (int*)d_ws;
    int* nvbuf = invK + (size_t)B_ * S_;
    unsigned short* qg  = (unsigned short*)(nvbuf + 16);
    unsigned short* kg  = qg + (size_t)B_ * S_ * U_;
    unsigned short* xTg = kg + (size_t)B_ * S_ * U_;
    unsigned short* wfg = xTg + (size_t)B_ * S_ * D_;

    zero_k<<<2048, 256, 0, stream>>>((float4*)outp, B_ * S_ * D_ / 4);
    scan_k<<<B_, 256, 0, stream>>>(mraw, invK, nvbuf);
    wfrag_k<<<48, 256, 0, stream>>>(Wq, Wk, wfg);
    prep_k<<<B_ * NT, 256, 0, stream>>>(x, invK, nvbuf, wfg, qg, kg, xTg);
    attn_k<<<1024, 256, 0, stream>>>(xTg, qg, kg, invK, nvbuf, outp);
}